// Round 26
// baseline (208.818 us; speedup 1.0000x reference)
//
#include <hip/hip_runtime.h>
#include <hip/hip_bf16.h>

#define DIM 512
#define BB 8
#define LL 8192
#define ML (BB * LL)  // 65536 rows

typedef __attribute__((ext_vector_type(4))) float f32x4;
typedef __attribute__((ext_vector_type(8))) short short8;

__device__ __forceinline__ unsigned short bf16_bits(float f) {
  __hip_bfloat16 h = __float2bfloat16(f);
  return *reinterpret_cast<unsigned short*>(&h);
}

// Packed tile-major GLOBAL layout (verified R10/R14/R16/R20): element (r,k) ->
// 8KB tile (r>>7, k>>5); offset (r&127)*32 + chunkpos*8 + (k&7),
// chunkpos = ((k>>3)&3) ^ ((r>>1)&3)  (T2 XOR pre-baked).
__device__ __forceinline__ size_t packA(int r, int k) {
  return ((size_t)((r >> 7) * 16 + (k >> 5))) * 4096 + (r & 127) * 32 +
         (((((k >> 3) & 3) ^ ((r >> 1) & 3))) << 3) + (k & 7);
}

// 64-row packed LDS layout (same scheme, half-tile): r in [0,64), c in [0,512)
__device__ __forceinline__ int ldsoff(int r, int c) {
  return (c >> 5) * 2048 + r * 32 +
         (((((c >> 3) & 3) ^ ((r >> 1) & 3))) << 3) + (c & 7);
}

// ---------------- weight prep: cast (or transpose-cast) into packed layout --
__global__ void prep_w(const float* __restrict__ src,
                       __hip_bfloat16* __restrict__ dst, int transpose,
                       const float* __restrict__ cw, float* __restrict__ cwt) {
  const int i = blockIdx.x * 256 + threadIdx.x;  // 0..262143
  if (transpose) {
    const int k = i >> 9, n = i & 511;
    dst[packA(n, k)] = __float2bfloat16(src[i]);
  } else {
    const int n = i >> 9, k = i & 511;
    dst[packA(n, k)] = __float2bfloat16(src[i]);
  }
  if (cwt != nullptr && i < DIM * 4) cwt[(i & 3) * DIM + (i >> 2)] = cw[i];
}

// ---------------- FULLY FUSED: conv -> GEMM1 -> l2norm -> GEMM2(gelu)
// -> GEMM3(+residual) per 64-row block (R20/R25 proven best, 175.9us).
// CHANGE vs R25: GEMM K-loop FULLY unrolled with loop-local temporaries --
// gives the register-pressure-aware scheduler freedom to pipeline loads
// across kt without the forced named-set liveness that made R22-R24 spill.
__global__ __launch_bounds__(512, 2) void fused_kernel(
    const float* __restrict__ x, const float* __restrict__ cwt,
    const float* __restrict__ cb, const __hip_bfloat16* __restrict__ wq,
    const __hip_bfloat16* __restrict__ w1t,
    const __hip_bfloat16* __restrict__ w2t, float* __restrict__ out) {
  __shared__ __hip_bfloat16 sX[16 * 2048];  // 64KB: xconv, later G
  __shared__ __hip_bfloat16 sC[16 * 2048];  // 64KB: C1 (lives to the end)
  __shared__ float ssL[64];
  const int tid = threadIdx.x;
  const int wv = tid >> 6, ln = tid & 63;
  const int idx = ln & 15, kg = ln >> 4;
  const int r0 = blockIdx.x * 64;
  const int kgx = ((kg ^ ((idx >> 1) & 3)) << 3);
  const int cbase = wv * 64;

  if (tid < 64) ssL[tid] = 0.0f;

  // ---- conv: wave wv computes rows gbase..gbase+7 -> sX (packed bf16) -----
  {
    const int gbase = r0 + wv * 8;
    const int seqstart = gbase & ~(LL - 1);  // sequence start of these rows
#pragma unroll
    for (int p = 0; p < 2; ++p) {
      const int d = (ln + p * 64) * 4;  // column quad; wave covers 1KB run
      const float4 cb4 = *(const float4*)(cb + d);
      float4 wk0 = *(const float4*)(cwt + 0 * DIM + d);
      float4 wk1 = *(const float4*)(cwt + 1 * DIM + d);
      float4 wk2 = *(const float4*)(cwt + 2 * DIM + d);
      float4 wk3 = *(const float4*)(cwt + 3 * DIM + d);
      const float4 z4 = make_float4(0.f, 0.f, 0.f, 0.f);
      float4 xm3 = (gbase - 3 >= seqstart)
                       ? *(const float4*)(x + (size_t)(gbase - 3) * DIM + d)
                       : z4;
      float4 xm2 = (gbase - 2 >= seqstart)
                       ? *(const float4*)(x + (size_t)(gbase - 2) * DIM + d)
                       : z4;
      float4 xm1 = (gbase - 1 >= seqstart)
                       ? *(const float4*)(x + (size_t)(gbase - 1) * DIM + d)
                       : z4;
#pragma unroll
      for (int i = 0; i < 8; ++i) {
        const float4 x0 =
            *(const float4*)(x + (size_t)(gbase + i) * DIM + d);
        float4 a;
        a.x = cb4.x + xm3.x * wk0.x + xm2.x * wk1.x + xm1.x * wk2.x +
              x0.x * wk3.x;
        a.y = cb4.y + xm3.y * wk0.y + xm2.y * wk1.y + xm1.y * wk2.y +
              x0.y * wk3.y;
        a.z = cb4.z + xm3.z * wk0.z + xm2.z * wk1.z + xm1.z * wk2.z +
              x0.z * wk3.z;
        a.w = cb4.w + xm3.w * wk0.w + xm2.w * wk1.w + xm1.w * wk2.w +
              x0.w * wk3.w;
        ushort4 o;
        o.x = bf16_bits(a.x);
        o.y = bf16_bits(a.y);
        o.z = bf16_bits(a.z);
        o.w = bf16_bits(a.w);
        *(ushort4*)((unsigned short*)sX + ldsoff(wv * 8 + i, d)) = o;
        xm3 = xm2;
        xm2 = xm1;
        xm1 = x0;
      }
    }
  }
  __syncthreads();  // sX (xconv) complete; ssL zero visible

  // per-wave packed-weight tile bases (wave's 64 n-rows = its col strip)
  const size_t wofs =
      (size_t)(wv >> 1) * 16 * 4096 + (size_t)((wv & 1) * 64) * 32;
  const __hip_bfloat16* tq = wq + wofs;
  const __hip_bfloat16* t1 = w1t + wofs;
  const __hip_bfloat16* t2 = w2t + wofs;

#define GEMM_LOOP(ASRC_EXPR, BPTR)                                          \
  _Pragma("unroll") for (int kt = 0; kt < 16; ++kt) {                       \
    short8 af[4], bf[4];                                                    \
    _Pragma("unroll") for (int mi = 0; mi < 4; ++mi) af[mi] =               \
        *(const short8*)(ASRC_EXPR + kt * 2048 + (mi * 16 + idx) * 32 + kgx); \
    _Pragma("unroll") for (int ni = 0; ni < 4; ++ni) bf[ni] =               \
        *(const short8*)(BPTR + kt * 4096 + (ni * 16 + idx) * 32 + kgx);    \
    _Pragma("unroll") for (int mi = 0; mi < 4; ++mi)                        \
        _Pragma("unroll") for (int ni = 0; ni < 4; ++ni) acc[mi][ni] =      \
            __builtin_amdgcn_mfma_f32_16x16x32_bf16(af[mi], bf[ni],         \
                                                    acc[mi][ni], 0, 0, 0);  \
  }

  // ---- GEMM1: C1 = xconv @ wq^T -> sC (bf16) + row sumsq -> ssL ----------
  {
    f32x4 acc[4][4] = {};
    GEMM_LOOP(sX, tq)
#pragma unroll
    for (int mi = 0; mi < 4; ++mi) {
#pragma unroll
      for (int j = 0; j < 4; ++j) {
        const int r = mi * 16 + kg * 4 + j;
        float ps = 0.0f;
#pragma unroll
        for (int ni = 0; ni < 4; ++ni) {
          const float v = acc[mi][ni][j];
          ps += v * v;
          sC[ldsoff(r, cbase + ni * 16 + idx)] = __float2bfloat16(v);
        }
        ps += __shfl_xor(ps, 1, 64);
        ps += __shfl_xor(ps, 2, 64);
        ps += __shfl_xor(ps, 4, 64);
        ps += __shfl_xor(ps, 8, 64);
        if (idx == 0) atomicAdd(&ssL[r], ps);
      }
    }
  }
  __syncthreads();  // sC + ssL complete; sX reads done -> may overwrite

  // ---- GEMM2: G = gelu(sc * (C1 @ w1)) -> sX (bf16) ----------------------
  {
    f32x4 acc[4][4] = {};
    GEMM_LOOP(sC, t1)
#pragma unroll
    for (int mi = 0; mi < 4; ++mi) {
#pragma unroll
      for (int j = 0; j < 4; ++j) {
        const int r = mi * 16 + kg * 4 + j;
        const float sc = 1.0f / fmaxf(sqrtf(ssL[r]), 1e-12f);
#pragma unroll
        for (int ni = 0; ni < 4; ++ni) {
          const float v = acc[mi][ni][j] * sc;
          const float ge = 0.5f * v * (1.0f + erff(v * 0.70710678118654752f));
          sX[ldsoff(r, cbase + ni * 16 + idx)] = __float2bfloat16(ge);
        }
      }
    }
  }
  __syncthreads();  // G complete

  // ---- GEMM3: out = sc*C1 + G @ w2 (f32, row-major) ----------------------
  {
    f32x4 acc[4][4] = {};
    GEMM_LOOP(sX, t2)
#pragma unroll
    for (int mi = 0; mi < 4; ++mi) {
#pragma unroll
      for (int j = 0; j < 4; ++j) {
        const int r = mi * 16 + kg * 4 + j;
        const float sc = 1.0f / fmaxf(sqrtf(ssL[r]), 1e-12f);
#pragma unroll
        for (int ni = 0; ni < 4; ++ni) {
          const int c = cbase + ni * 16 + idx;
          out[(size_t)(r0 + r) * DIM + c] =
              acc[mi][ni][j] + sc * __bfloat162float(sC[ldsoff(r, c)]);
        }
      }
    }
  }
#undef GEMM_LOOP
}

extern "C" void kernel_launch(void* const* d_in, const int* in_sizes, int n_in,
                              void* d_out, int out_size, void* d_ws,
                              size_t ws_size, hipStream_t stream) {
  const float* x = (const float*)d_in[0];
  const float* cw = (const float*)d_in[1];
  const float* cb = (const float*)d_in[2];
  const float* qw = (const float*)d_in[3];
  const float* w1 = (const float*)d_in[4];
  const float* w2 = (const float*)d_in[5];
  float* out = (float*)d_out;

  // ws layout (high-water ~1.6 MB):
  //   [0, 512K)          wq packed bf16
  //   [512K, 1M)         w1t packed bf16
  //   [1M, 1.5M)         w2t packed bf16
  //   [1.5M, 1.5M+8K)    cwt f32 [4][512]
  char* ws = (char*)d_ws;
  __hip_bfloat16* wqp = (__hip_bfloat16*)ws;
  __hip_bfloat16* w1p = wqp + DIM * DIM;
  __hip_bfloat16* w2p = w1p + DIM * DIM;
  float* cwt = (float*)(ws + 3 * 524288);

  prep_w<<<DIM * DIM / 256, 256, 0, stream>>>(qw, wqp, 0, cw, cwt);
  prep_w<<<DIM * DIM / 256, 256, 0, stream>>>(w1, w1p, 1, nullptr, nullptr);
  prep_w<<<DIM * DIM / 256, 256, 0, stream>>>(w2, w2p, 1, nullptr, nullptr);
  fused_kernel<<<ML / 64, 512, 0, stream>>>(x, cwt, cb, wqp, w1p, w2p, out);
}

// Round 27
// 175.164 us; speedup vs baseline: 1.1921x; 1.1921x over previous
//
#include <hip/hip_runtime.h>
#include <hip/hip_bf16.h>

#define DIM 512
#define BB 8
#define LL 8192
#define ML (BB * LL)  // 65536 rows

typedef __attribute__((ext_vector_type(4))) float f32x4;
typedef __attribute__((ext_vector_type(8))) short short8;

__device__ __forceinline__ unsigned short bf16_bits(float f) {
  __hip_bfloat16 h = __float2bfloat16(f);
  return *reinterpret_cast<unsigned short*>(&h);
}

// Packed tile-major GLOBAL layout (verified R10/R14/R16/R20): element (r,k) ->
// 8KB tile (r>>7, k>>5); offset (r&127)*32 + chunkpos*8 + (k&7),
// chunkpos = ((k>>3)&3) ^ ((r>>1)&3)  (T2 XOR pre-baked).
__device__ __forceinline__ size_t packA(int r, int k) {
  return ((size_t)((r >> 7) * 16 + (k >> 5))) * 4096 + (r & 127) * 32 +
         (((((k >> 3) & 3) ^ ((r >> 1) & 3))) << 3) + (k & 7);
}

// 64-row packed LDS layout (same scheme, half-tile): r in [0,64), c in [0,512)
__device__ __forceinline__ int ldsoff(int r, int c) {
  return (c >> 5) * 2048 + r * 32 +
         (((((c >> 3) & 3) ^ ((r >> 1) & 3))) << 3) + (c & 7);
}

// ---------------- weight prep: cast (or transpose-cast) into packed layout --
__global__ void prep_w(const float* __restrict__ src,
                       __hip_bfloat16* __restrict__ dst, int transpose,
                       const float* __restrict__ cw, float* __restrict__ cwt) {
  const int i = blockIdx.x * 256 + threadIdx.x;  // 0..262143
  if (transpose) {
    const int k = i >> 9, n = i & 511;
    dst[packA(n, k)] = __float2bfloat16(src[i]);
  } else {
    const int n = i >> 9, k = i & 511;
    dst[packA(n, k)] = __float2bfloat16(src[i]);
  }
  if (cwt != nullptr && i < DIM * 4) cwt[(i & 3) * DIM + (i >> 2)] = cw[i];
}

// ---------------- FULLY FUSED: conv -> GEMM1 -> l2norm -> GEMM2(gelu)
// -> GEMM3(+residual) per 64-row block; xconv/C1/G never touch HBM.
// 8 waves, 1 block/CU, unroll-2 K loop — R20/R25 proven best (175.4us,
// no spill, VGPR 128). All tested alternatives regressed:
//   sync/pipeline structure x8 (R4-R8), staging source x3 (R9/R10/R14),
//   occupancy x2 (R19/R21), register pipelining x4 (R22-R24, R26 spills).
__global__ __launch_bounds__(512, 2) void fused_kernel(
    const float* __restrict__ x, const float* __restrict__ cwt,
    const float* __restrict__ cb, const __hip_bfloat16* __restrict__ wq,
    const __hip_bfloat16* __restrict__ w1t,
    const __hip_bfloat16* __restrict__ w2t, float* __restrict__ out) {
  __shared__ __hip_bfloat16 sX[16 * 2048];  // 64KB: xconv, later G
  __shared__ __hip_bfloat16 sC[16 * 2048];  // 64KB: C1 (lives to the end)
  __shared__ float ssL[64];
  const int tid = threadIdx.x;
  const int wv = tid >> 6, ln = tid & 63;
  const int idx = ln & 15, kg = ln >> 4;
  const int r0 = blockIdx.x * 64;
  const int kgx = ((kg ^ ((idx >> 1) & 3)) << 3);
  const int cbase = wv * 64;

  if (tid < 64) ssL[tid] = 0.0f;

  // ---- conv: wave wv computes rows gbase..gbase+7 -> sX (packed bf16) -----
  {
    const int gbase = r0 + wv * 8;
    const int seqstart = gbase & ~(LL - 1);  // sequence start of these rows
#pragma unroll
    for (int p = 0; p < 2; ++p) {
      const int d = (ln + p * 64) * 4;  // column quad; wave covers 1KB run
      const float4 cb4 = *(const float4*)(cb + d);
      float4 wk0 = *(const float4*)(cwt + 0 * DIM + d);
      float4 wk1 = *(const float4*)(cwt + 1 * DIM + d);
      float4 wk2 = *(const float4*)(cwt + 2 * DIM + d);
      float4 wk3 = *(const float4*)(cwt + 3 * DIM + d);
      const float4 z4 = make_float4(0.f, 0.f, 0.f, 0.f);
      float4 xm3 = (gbase - 3 >= seqstart)
                       ? *(const float4*)(x + (size_t)(gbase - 3) * DIM + d)
                       : z4;
      float4 xm2 = (gbase - 2 >= seqstart)
                       ? *(const float4*)(x + (size_t)(gbase - 2) * DIM + d)
                       : z4;
      float4 xm1 = (gbase - 1 >= seqstart)
                       ? *(const float4*)(x + (size_t)(gbase - 1) * DIM + d)
                       : z4;
#pragma unroll
      for (int i = 0; i < 8; ++i) {
        const float4 x0 =
            *(const float4*)(x + (size_t)(gbase + i) * DIM + d);
        float4 a;
        a.x = cb4.x + xm3.x * wk0.x + xm2.x * wk1.x + xm1.x * wk2.x +
              x0.x * wk3.x;
        a.y = cb4.y + xm3.y * wk0.y + xm2.y * wk1.y + xm1.y * wk2.y +
              x0.y * wk3.y;
        a.z = cb4.z + xm3.z * wk0.z + xm2.z * wk1.z + xm1.z * wk2.z +
              x0.z * wk3.z;
        a.w = cb4.w + xm3.w * wk0.w + xm2.w * wk1.w + xm1.w * wk2.w +
              x0.w * wk3.w;
        ushort4 o;
        o.x = bf16_bits(a.x);
        o.y = bf16_bits(a.y);
        o.z = bf16_bits(a.z);
        o.w = bf16_bits(a.w);
        *(ushort4*)((unsigned short*)sX + ldsoff(wv * 8 + i, d)) = o;
        xm3 = xm2;
        xm2 = xm1;
        xm1 = x0;
      }
    }
  }
  __syncthreads();  // sX (xconv) complete; ssL zero visible

  // per-wave packed-weight tile bases (wave's 64 n-rows = its col strip)
  const size_t wofs =
      (size_t)(wv >> 1) * 16 * 4096 + (size_t)((wv & 1) * 64) * 32;
  const __hip_bfloat16* tq = wq + wofs;
  const __hip_bfloat16* t1 = w1t + wofs;
  const __hip_bfloat16* t2 = w2t + wofs;

#define GEMM_LOOP(ASRC_EXPR, BPTR)                                          \
  _Pragma("unroll 2") for (int kt = 0; kt < 16; ++kt) {                     \
    short8 af[4], bf[4];                                                    \
    _Pragma("unroll") for (int mi = 0; mi < 4; ++mi) af[mi] =               \
        *(const short8*)(ASRC_EXPR + kt * 2048 + (mi * 16 + idx) * 32 + kgx); \
    _Pragma("unroll") for (int ni = 0; ni < 4; ++ni) bf[ni] =               \
        *(const short8*)(BPTR + kt * 4096 + (ni * 16 + idx) * 32 + kgx);    \
    _Pragma("unroll") for (int mi = 0; mi < 4; ++mi)                        \
        _Pragma("unroll") for (int ni = 0; ni < 4; ++ni) acc[mi][ni] =      \
            __builtin_amdgcn_mfma_f32_16x16x32_bf16(af[mi], bf[ni],         \
                                                    acc[mi][ni], 0, 0, 0);  \
  }

  // ---- GEMM1: C1 = xconv @ wq^T -> sC (bf16) + row sumsq -> ssL ----------
  {
    f32x4 acc[4][4] = {};
    GEMM_LOOP(sX, tq)
#pragma unroll
    for (int mi = 0; mi < 4; ++mi) {
#pragma unroll
      for (int j = 0; j < 4; ++j) {
        const int r = mi * 16 + kg * 4 + j;
        float ps = 0.0f;
#pragma unroll
        for (int ni = 0; ni < 4; ++ni) {
          const float v = acc[mi][ni][j];
          ps += v * v;
          sC[ldsoff(r, cbase + ni * 16 + idx)] = __float2bfloat16(v);
        }
        ps += __shfl_xor(ps, 1, 64);
        ps += __shfl_xor(ps, 2, 64);
        ps += __shfl_xor(ps, 4, 64);
        ps += __shfl_xor(ps, 8, 64);
        if (idx == 0) atomicAdd(&ssL[r], ps);
      }
    }
  }
  __syncthreads();  // sC + ssL complete; sX reads done -> may overwrite

  // ---- GEMM2: G = gelu(sc * (C1 @ w1)) -> sX (bf16) ----------------------
  {
    f32x4 acc[4][4] = {};
    GEMM_LOOP(sC, t1)
#pragma unroll
    for (int mi = 0; mi < 4; ++mi) {
#pragma unroll
      for (int j = 0; j < 4; ++j) {
        const int r = mi * 16 + kg * 4 + j;
        const float sc = 1.0f / fmaxf(sqrtf(ssL[r]), 1e-12f);
#pragma unroll
        for (int ni = 0; ni < 4; ++ni) {
          const float v = acc[mi][ni][j] * sc;
          const float ge = 0.5f * v * (1.0f + erff(v * 0.70710678118654752f));
          sX[ldsoff(r, cbase + ni * 16 + idx)] = __float2bfloat16(ge);
        }
      }
    }
  }
  __syncthreads();  // G complete

  // ---- GEMM3: out = sc*C1 + G @ w2 (f32, row-major) ----------------------
  {
    f32x4 acc[4][4] = {};
    GEMM_LOOP(sX, t2)
#pragma unroll
    for (int mi = 0; mi < 4; ++mi) {
#pragma unroll
      for (int j = 0; j < 4; ++j) {
        const int r = mi * 16 + kg * 4 + j;
        const float sc = 1.0f / fmaxf(sqrtf(ssL[r]), 1e-12f);
#pragma unroll
        for (int ni = 0; ni < 4; ++ni) {
          const int c = cbase + ni * 16 + idx;
          out[(size_t)(r0 + r) * DIM + c] =
              acc[mi][ni][j] + sc * __bfloat162float(sC[ldsoff(r, c)]);
        }
      }
    }
  }
#undef GEMM_LOOP
}

extern "C" void kernel_launch(void* const* d_in, const int* in_sizes, int n_in,
                              void* d_out, int out_size, void* d_ws,
                              size_t ws_size, hipStream_t stream) {
  const float* x = (const float*)d_in[0];
  const float* cw = (const float*)d_in[1];
  const float* cb = (const float*)d_in[2];
  const float* qw = (const float*)d_in[3];
  const float* w1 = (const float*)d_in[4];
  const float* w2 = (const float*)d_in[5];
  float* out = (float*)d_out;

  // ws layout (high-water ~1.6 MB):
  //   [0, 512K)          wq packed bf16
  //   [512K, 1M)         w1t packed bf16
  //   [1M, 1.5M)         w2t packed bf16
  //   [1.5M, 1.5M+8K)    cwt f32 [4][512]
  char* ws = (char*)d_ws;
  __hip_bfloat16* wqp = (__hip_bfloat16*)ws;
  __hip_bfloat16* w1p = wqp + DIM * DIM;
  __hip_bfloat16* w2p = w1p + DIM * DIM;
  float* cwt = (float*)(ws + 3 * 524288);

  prep_w<<<DIM * DIM / 256, 256, 0, stream>>>(qw, wqp, 0, cw, cwt);
  prep_w<<<DIM * DIM / 256, 256, 0, stream>>>(w1, w1p, 1, nullptr, nullptr);
  prep_w<<<DIM * DIM / 256, 256, 0, stream>>>(w2, w2p, 1, nullptr, nullptr);
  fused_kernel<<<ML / 64, 512, 0, stream>>>(x, cwt, cb, wqp, w1p, w2p, out);
}